// Round 13
// baseline (149.535 us; speedup 1.0000x reference)
//
#include <hip/hip_runtime.h>
#include <cmath>

#define B_ROWS 4096
#define T_LEN  2048
#define TB     16                 // timesteps per register block
#define NBLK   (T_LEN / TB)       // 128 (even)

typedef float f32x2 __attribute__((ext_vector_type(2)));

// ---- R2/R4/R7-proven SCALAR DPP-add: update_dpp(old=0, bound_ctrl=1).
// All reduce math stays scalar float; an asm barrier upstream prevents the
// SLP vectorizer from pairing these adds into v_pk ops (R12 failure mode).
template<int CTRL>
__device__ __forceinline__ float dpp_add(float x) {
  int y = __builtin_amdgcn_update_dpp(0, __builtin_bit_cast(int, x),
                                      CTRL, 0xf, 0xf, true);
  return x + __builtin_bit_cast(float, y);
}
// 8-lane allreduce: first 3 stages of the R7-proven 16-lane butterfly.
__device__ __forceinline__ float allreduce8(float x) {
  x = dpp_add<0xB1>(x);    // xor 1 (within quad)
  x = dpp_add<0x4E>(x);    // xor 2 (within quad)
  x = dpp_add<0x141>(x);   // row_half_mirror: cross-quad within 8 lanes
  return x;                // all 8 lanes of the group hold the sum
}

struct Coef { float a[8]; float K; };   // sigma(u) ~ 0.5 + u*q(u^2), |u|<=K

// One register block: 16 timesteps of (eps,hs) = 8 float4 = 32 VGPRs.
struct Blk { float4 q[8]; };
__device__ __forceinline__ void load_blk(const float4* __restrict__ src,
                                         Blk& b) {
#pragma unroll
  for (int i = 0; i < 8; ++i) b.q[i] = src[i];   // broadcast within 8 lanes
}

struct Pre { float deps[TB - 1]; float hsn[TB]; float eps15; };
__device__ __forceinline__ void extract(const Blk& b, Pre& p) {
  float eps[TB];
#pragma unroll
  for (int i = 0; i < 8; ++i) {
    eps[2 * i]       = b.q[i].x;
    p.hsn[2 * i]     = -b.q[i].y;
    eps[2 * i + 1]   = b.q[i].z;
    p.hsn[2 * i + 1] = -b.q[i].w;
  }
#pragma unroll
  for (int t = 0; t < TB - 1; ++t) p.deps[t] = eps[t + 1] - eps[t];
  p.eps15 = eps[TB - 1];
}

// 16 steps, u-form, 2 units/lane (units j and j+8).  CHAIN per step:
//   u'fma -> med3 -> u2 -> 3 Estrin fma -> v1 fma -> presum add ->
//   3x scalar dpp-pair -> u'fma            (~78 cy, no trans ops)
__device__ __forceinline__ void compute16(
    const Pre& p, float nextq0x, bool peek, f32x2& u, const f32x2* A,
    float K, f32x2 w0p, f32x2 w1p, f32x2 c0p, f32x2 c1p, f32x2 h0p,
    f32x2 h1p, int j, float* __restrict__ outp) {
  float keep0 = 0.0f, keep1 = 0.0f;
#pragma unroll
  for (int t = 0; t < TB; ++t) {
    f32x2 uc;
    uc.x = __builtin_amdgcn_fmed3f(u.x, -K, K);
    uc.y = __builtin_amdgcn_fmed3f(u.y, -K, K);
    f32x2 u2 = uc * uc;                          // packed poly (no DPP risk)
    f32x2 e0 = __builtin_elementwise_fma(A[1], u2, A[0]);
    f32x2 e1 = __builtin_elementwise_fma(A[3], u2, A[2]);
    f32x2 e2 = __builtin_elementwise_fma(A[5], u2, A[4]);
    f32x2 e3 = __builtin_elementwise_fma(A[7], u2, A[6]);
    f32x2 u4 = u2 * u2;
    f32x2 d0 = __builtin_elementwise_fma(e1, u4, e0);
    f32x2 d1 = __builtin_elementwise_fma(e3, u4, e2);
    f32x2 u8 = u4 * u4;
    f32x2 qq = __builtin_elementwise_fma(d1, u8, d0);    // q(u^2)
    f32x2 v1 = __builtin_elementwise_fma(c1p * uc, qq, h1p);  // c1*sigma
    f32x2 v0 = __builtin_elementwise_fma(c0p * uc, qq, h0p);  // c0*sigma
    float a1 = v1.x + v1.y;                      // in-lane pair presum
    float a0 = v0.x + v0.y;
    asm volatile("" : "+v"(a0), "+v"(a1));       // scalar regs; block SLP
    float s1 = allreduce8(a1);                   // chain: gamma-path sum
    float s0 = allreduce8(a0);                   // off-chain: output sum
    // off-chain: u-recurrence side inputs
    float dep = (t < TB - 1) ? p.deps[t]
                             : (peek ? (nextq0x - p.eps15) : 0.0f);
    float hw0 = w1p.x * p.hsn[t];                // -hs * w1 (per unit)
    float hw1 = w1p.y * p.hsn[t];
    float P0  = fmaf(w0p.x, dep, u.x);
    float P1  = fmaf(w0p.y, dep, u.y);
    u.x = fmaf(hw0, s1, P0);                     // chain tail
    u.y = fmaf(hw1, s1, P1);
    keep0 = (t < 8 && j == t)      ? s0 : keep0; // branchless latch
    keep1 = (t >= 8 && j == t - 8) ? s0 : keep1;
  }
  outp[j]     = keep0;    // contiguous 16 floats per row per block
  outp[8 + j] = keep1;
}

__global__ __launch_bounds__(64) void gsm_scan_kernel(
    const float* __restrict__ inp, const float* __restrict__ W1f,
    const float* __restrict__ b1f, const float* __restrict__ W2f,
    float* __restrict__ out, const Coef cf) {
  const int lane = threadIdx.x;       // 0..63
  const int g    = lane >> 3;         // row within wave, 0..7
  const int j    = lane & 7;          // lane within row; units j and j+8
  const int row  = (blockIdx.x << 3) + g;

  f32x2 w0p, w1p, bp, w2p;
  w0p.x = W1f[j];      w0p.y = W1f[j + 8];
  w1p.x = W1f[16 + j]; w1p.y = W1f[24 + j];
  bp.x  = b1f[j];      bp.y  = b1f[j + 8];
  w2p.x = W2f[j];      w2p.y = W2f[j + 8];
  f32x2 c0p = w2p * w0p;               // output-path coeff
  f32x2 c1p = (w2p * w1p) * 0.1f;      // gamma-path coeff (inv_eta folded)
  f32x2 h0p = c0p * 0.5f;
  f32x2 h1p = c1p * 0.5f;
  f32x2 A[8];
#pragma unroll
  for (int k = 0; k < 8; ++k) { A[k].x = cf.a[k]; A[k].y = cf.a[k]; }

  const float4* src = (const float4*)(inp + (size_t)row * (2 * T_LEN));
  float* outrow = out + (size_t)row * T_LEN;

  Blk Ab, Bb;
  Pre p;
  load_blk(src, Ab);                 // block 0
  load_blk(src + 8, Bb);             // block 1
  f32x2 u;
  u.x = fmaf(Ab.q[0].x, w0p.x, bp.x);   // u0 = eps0*w0 + b (gamma0 = 0)
  u.y = fmaf(Ab.q[0].x, w0p.y, bp.y);

#pragma unroll 1
  for (int b = 0; b < NBLK; b += 2) {
    // ---- phase 1: block b from Ab; prefetch b+2 into Ab's dead regs
    extract(Ab, p);
    if (b + 2 < NBLK) load_blk(src + (size_t)(b + 2) * 8, Ab);
    compute16(p, Bb.q[0].x, true, u, A, cf.K, w0p, w1p, c0p, c1p, h0p, h1p,
              j, outrow + b * TB);
    // ---- phase 2: block b+1 from Bb; prefetch b+3 into Bb's regs
    extract(Bb, p);
    if (b + 3 < NBLK) load_blk(src + (size_t)(b + 3) * 8, Bb);
    compute16(p, Ab.q[0].x, (b + 2 < NBLK), u, A, cf.K, w0p, w1p, c0p, c1p,
              h0p, h1p, j, outrow + (b + 1) * TB);
  }
}

// ---- host-side: LS fit of sigma(u)-0.5 with odd poly, deg 15, on [-K,K] ----
static void fit_sigma_coeffs(double K, Coef& cf) {
  const int N = 1024;
  double M[8][8] = {{0}}, bv[8] = {0}, a[8];
  for (int i = 0; i < N; ++i) {
    double th = 3.14159265358979323846 * (i + 0.5) / (2.0 * N);
    double s  = cos(th);                 // Chebyshev-clustered in (0,1]
    double u  = K * s;
    double f  = 1.0 / (1.0 + exp(-u)) - 0.5;
    double pk[8]; double sp = s;
    for (int k = 0; k < 8; ++k) { pk[k] = sp; sp *= s * s; }
    for (int r = 0; r < 8; ++r) {
      bv[r] += f * pk[r];
      for (int c = 0; c < 8; ++c) M[r][c] += pk[r] * pk[c];
    }
  }
  for (int col = 0; col < 8; ++col) {         // Gauss, partial pivoting
    int piv = col;
    for (int r = col + 1; r < 8; ++r)
      if (fabs(M[r][col]) > fabs(M[piv][col])) piv = r;
    if (piv != col) {
      for (int c = 0; c < 8; ++c) { double t = M[col][c]; M[col][c] = M[piv][c]; M[piv][c] = t; }
      double t = bv[col]; bv[col] = bv[piv]; bv[piv] = t;
    }
    for (int r = col + 1; r < 8; ++r) {
      double fac = M[r][col] / M[col][col];
      for (int c = col; c < 8; ++c) M[r][c] -= fac * M[col][c];
      bv[r] -= fac * bv[col];
    }
  }
  for (int r = 7; r >= 0; --r) {
    double s2 = bv[r];
    for (int c = r + 1; c < 8; ++c) s2 -= M[r][c] * a[c];
    a[r] = s2 / M[r][r];
  }
  double Kp = K;                              // rescale s=u/K -> monomials in u
  for (int k = 0; k < 8; ++k) { cf.a[k] = (float)(a[k] / Kp); Kp *= K * K; }
  cf.K = (float)K;
}

extern "C" void kernel_launch(void* const* d_in, const int* in_sizes, int n_in,
                              void* d_out, int out_size, void* d_ws,
                              size_t ws_size, hipStream_t stream) {
  const float* inp = (const float*)d_in[0];   // (B, T, 2) f32
  const float* W1  = (const float*)d_in[1];   // (2, 16)
  const float* b1  = (const float*)d_in[2];   // (16,)
  const float* W2  = (const float*)d_in[3];   // (16, 1)
  // d_in[4] = b2 : unused by the reference computation
  float* out = (float*)d_out;                 // (B, T) f32

  Coef cf;
  fit_sigma_coeffs(6.5, cf);   // deterministic, host-only, runs at capture

  dim3 grid(B_ROWS / 8);   // 512 waves, 8 rows/wave, 8 lanes/row, 2 units/lane
  dim3 block(64);
  hipLaunchKernelGGL(gsm_scan_kernel, grid, block, 0, stream,
                     inp, W1, b1, W2, out, cf);
}

// Round 14
// 120.414 us; speedup vs baseline: 1.2418x; 1.2418x over previous
//
#include <hip/hip_runtime.h>
#include <cmath>

#define B_ROWS 4096
#define T_LEN  2048
#define TB     16                 // timesteps per register block
#define NBLK   (T_LEN / TB)       // 128 (even)

// ---- proven scalar DPP-add primitive (R2/R4/R7/R11) ----
template<int CTRL>
__device__ __forceinline__ float dpp_add(float x) {
  int y = __builtin_amdgcn_update_dpp(0, __builtin_bit_cast(int, x),
                                      CTRL, 0xf, 0xf, true);
  return x + __builtin_bit_cast(float, y);
}
// 16-lane allreduce (chain path, s1): proven ctrl sequence.
__device__ __forceinline__ float allreduce16(float x) {
  x = dpp_add<0xB1>(x);    // xor 1
  x = dpp_add<0x4E>(x);    // xor 2
  x = dpp_add<0x141>(x);   // xor 7 (== xor4 effect after quad stages)
  x = dpp_add<0x140>(x);   // xor 15 (== xor8 effect)
  return x;
}

struct Coef { float a[8]; float K; };   // sigma(u) ~ 0.5 + u*q(u^2), |u|<=K

// One register block: 16 timesteps of (eps,hs) = 8 float4 = 32 VGPRs.
struct Blk { float4 q[8]; };
__device__ __forceinline__ void load_blk(const float4* __restrict__ src,
                                         Blk& b) {
#pragma unroll
  for (int i = 0; i < 8; ++i) b.q[i] = src[i];   // broadcast within 16 lanes
}

struct Pre { float dpre[TB - 1]; float hwn[TB]; float eps15; };
__device__ __forceinline__ void extract(const Blk& b, float w0j, float w1j,
                                        Pre& p) {
  float eps[TB];
#pragma unroll
  for (int i = 0; i < 8; ++i) {
    eps[2 * i]       = b.q[i].x;
    p.hwn[2 * i]     = -b.q[i].y * w1j;
    eps[2 * i + 1]   = b.q[i].z;
    p.hwn[2 * i + 1] = -b.q[i].w * w1j;
  }
#pragma unroll
  for (int t = 0; t < TB - 1; ++t) p.dpre[t] = (eps[t + 1] - eps[t]) * w0j;
  p.eps15 = eps[TB - 1];
}

// 16 steps, u-form (u = z1).  CHAIN per step (~84 cy, no trans ops):
//   u'fma -> med3 -> u2 -> Estrin b -> d -> q -> v1 -> allreduce16 -> u'fma
// The s0/output path is now just "V[t] = v0" per step; the reduction is a
// DEFERRED block-end reduce-scatter (30 dpp-adds + 15 selects for all 16
// outputs, vs 16 butterflies = 128 instr + latches).
__device__ __forceinline__ void compute16(const Pre& p, float nextq0x,
                                          bool peek, float& u, const Coef cf,
                                          float w0j, float c0j, float c1j,
                                          float h0, float h1, int j,
                                          bool hi8, bool hi4, bool hi2,
                                          bool hi1,
                                          float* __restrict__ outp) {
  float V[TB];
#pragma unroll
  for (int t = 0; t < TB; ++t) {
    float uc  = __builtin_amdgcn_fmed3f(u, -cf.K, cf.K);   // clamp
    float u2  = uc * uc;
    float c1u = c1j * uc;                  // parallel with u2
    float c0u = c0j * uc;
    float b0 = fmaf(cf.a[1], u2, cf.a[0]);
    float b1 = fmaf(cf.a[3], u2, cf.a[2]);
    float b2 = fmaf(cf.a[5], u2, cf.a[4]);
    float b3 = fmaf(cf.a[7], u2, cf.a[6]);
    float u4 = u2 * u2;
    float d0 = fmaf(b1, u4, b0);
    float d1 = fmaf(b3, u4, b2);
    float u8 = u4 * u4;
    float q  = fmaf(d1, u8, d0);           // q(u^2)
    float v1 = fmaf(c1u, q, h1);           // c1 * sigma  (chain)
    V[t]     = fmaf(c0u, q, h0);           // c0 * sigma  (saved, no reduce)
    float s1 = allreduce16(v1);            // gamma-path sum (chain)
    float dpre_t = (t < TB - 1)
                     ? p.dpre[t]
                     : (peek ? ((nextq0x - p.eps15) * w0j) : 0.0f);
    float P = u + dpre_t;                  // off-chain
    u = fmaf(p.hwn[t], s1, P);             // u' (chain tail)
  }
  // ---- deferred reduce-scatter: lane j <- sum over lanes of V[j] ----
  // stages pair lanes by xor {15,7,2,1} (independent generators -> each
  // lane accumulates all 16 distinct lanes); renames keep output (j&8)+
  // (j&4)+(j&2)+k so the final select yields output index j exactly.
#pragma unroll
  for (int t = 0; t < TB; ++t) V[t] = dpp_add<0x140>(V[t]);  // xor 15
  float W[8];
#pragma unroll
  for (int k = 0; k < 8; ++k) W[k] = hi8 ? V[k + 8] : V[k];
#pragma unroll
  for (int k = 0; k < 8; ++k) W[k] = dpp_add<0x141>(W[k]);   // xor 7
  float X[4];
#pragma unroll
  for (int k = 0; k < 4; ++k) X[k] = hi4 ? W[k + 4] : W[k];
#pragma unroll
  for (int k = 0; k < 4; ++k) X[k] = dpp_add<0x4E>(X[k]);    // xor 2
  float Y0 = hi2 ? X[2] : X[0];
  float Y1 = hi2 ? X[3] : X[1];
  Y0 = dpp_add<0xB1>(Y0);                                    // xor 1
  Y1 = dpp_add<0xB1>(Y1);
  outp[j] = hi1 ? Y1 : Y0;   // 16 consecutive floats per row per block
}

__global__ __launch_bounds__(64) void gsm_scan_kernel(
    const float* __restrict__ inp, const float* __restrict__ W1f,
    const float* __restrict__ b1f, const float* __restrict__ W2f,
    float* __restrict__ out, const Coef cf) {
  const int lane = threadIdx.x;       // 0..63
  const int grp  = lane >> 4;         // row within wave, 0..3
  const int j    = lane & 15;         // hidden unit
  const int row  = (blockIdx.x << 2) + grp;
  const bool hi8 = (j & 8) != 0, hi4 = (j & 4) != 0,
             hi2 = (j & 2) != 0, hi1 = (j & 1) != 0;

  const float w0j = W1f[j];
  const float w1j = W1f[16 + j];
  const float bj  = b1f[j];
  const float w2j = W2f[j];
  const float c0j = w2j * w0j;          // output-path coefficient
  const float c1j = 0.1f * w2j * w1j;   // gamma-path coeff (inv_eta folded)
  const float h0  = 0.5f * c0j;
  const float h1  = 0.5f * c1j;

  const float4* src = (const float4*)(inp + (size_t)row * (2 * T_LEN));
  float* outrow = out + (size_t)row * T_LEN;

  Blk A, Bb;
  Pre p;
  load_blk(src, A);                  // block 0
  load_blk(src + 8, Bb);             // block 1
  float u = fmaf(A.q[0].x, w0j, bj);   // u0 = eps0*w0 + b  (gamma0 = 0)

#pragma unroll 1
  for (int b = 0; b < NBLK; b += 2) {
    // ---- phase 1: block b from A; prefetch b+2 into A's (now dead) regs
    extract(A, w0j, w1j, p);
    if (b + 2 < NBLK) load_blk(src + (size_t)(b + 2) * 8, A);
    compute16(p, Bb.q[0].x, true, u, cf, w0j, c0j, c1j, h0, h1, j,
              hi8, hi4, hi2, hi1, outrow + b * TB);
    // ---- phase 2: block b+1 from Bb; prefetch b+3 into Bb's regs
    extract(Bb, w0j, w1j, p);
    if (b + 3 < NBLK) load_blk(src + (size_t)(b + 3) * 8, Bb);
    compute16(p, A.q[0].x, (b + 2 < NBLK), u, cf, w0j, c0j, c1j, h0, h1, j,
              hi8, hi4, hi2, hi1, outrow + (b + 1) * TB);
  }
}

// ---- host-side: LS fit of sigma(u)-0.5 with odd poly, deg 15, on [-K,K] ----
static void fit_sigma_coeffs(double K, Coef& cf) {
  const int N = 1024;
  double M[8][8] = {{0}}, bv[8] = {0}, a[8];
  for (int i = 0; i < N; ++i) {
    double th = 3.14159265358979323846 * (i + 0.5) / (2.0 * N);
    double s  = cos(th);                 // Chebyshev-clustered in (0,1]
    double u  = K * s;
    double f  = 1.0 / (1.0 + exp(-u)) - 0.5;
    double pk[8]; double sp = s;
    for (int k = 0; k < 8; ++k) { pk[k] = sp; sp *= s * s; }
    for (int r = 0; r < 8; ++r) {
      bv[r] += f * pk[r];
      for (int c = 0; c < 8; ++c) M[r][c] += pk[r] * pk[c];
    }
  }
  for (int col = 0; col < 8; ++col) {         // Gauss, partial pivoting
    int piv = col;
    for (int r = col + 1; r < 8; ++r)
      if (fabs(M[r][col]) > fabs(M[piv][col])) piv = r;
    if (piv != col) {
      for (int c = 0; c < 8; ++c) { double t = M[col][c]; M[col][c] = M[piv][c]; M[piv][c] = t; }
      double t = bv[col]; bv[col] = bv[piv]; bv[piv] = t;
    }
    for (int r = col + 1; r < 8; ++r) {
      double fac = M[r][col] / M[col][col];
      for (int c = col; c < 8; ++c) M[r][c] -= fac * M[col][c];
      bv[r] -= fac * bv[col];
    }
  }
  for (int r = 7; r >= 0; --r) {
    double s2 = bv[r];
    for (int c = r + 1; c < 8; ++c) s2 -= M[r][c] * a[c];
    a[r] = s2 / M[r][r];
  }
  double Kp = K;                              // rescale s=u/K -> monomials in u
  for (int k = 0; k < 8; ++k) { cf.a[k] = (float)(a[k] / Kp); Kp *= K * K; }
  cf.K = (float)K;
}

extern "C" void kernel_launch(void* const* d_in, const int* in_sizes, int n_in,
                              void* d_out, int out_size, void* d_ws,
                              size_t ws_size, hipStream_t stream) {
  const float* inp = (const float*)d_in[0];   // (B, T, 2) f32
  const float* W1  = (const float*)d_in[1];   // (2, 16)
  const float* b1  = (const float*)d_in[2];   // (16,)
  const float* W2  = (const float*)d_in[3];   // (16, 1)
  // d_in[4] = b2 : unused by the reference computation
  float* out = (float*)d_out;                 // (B, T) f32

  Coef cf;
  fit_sigma_coeffs(6.5, cf);   // deterministic, host-only, runs at capture

  dim3 grid(B_ROWS / 4);   // 1024 waves = 1 per SIMD; wall = steps x chain
  dim3 block(64);
  hipLaunchKernelGGL(gsm_scan_kernel, grid, block, 0, stream,
                     inp, W1, b1, W2, out, cf);
}

// Round 15
// 120.145 us; speedup vs baseline: 1.2446x; 1.0022x over previous
//
#include <hip/hip_runtime.h>
#include <cmath>

#define B_ROWS 4096
#define T_LEN  2048
#define TB     16                 // timesteps per register block
#define NBLK   (T_LEN / TB)       // 128 (power of 2, even)

// ---- proven scalar DPP-add primitive (R2/R4/R7/R11/R14) ----
template<int CTRL>
__device__ __forceinline__ float dpp_add(float x) {
  int y = __builtin_amdgcn_update_dpp(0, __builtin_bit_cast(int, x),
                                      CTRL, 0xf, 0xf, true);
  return x + __builtin_bit_cast(float, y);
}
// 16-lane allreduce (chain path, s1): proven ctrl sequence.
__device__ __forceinline__ float allreduce16(float x) {
  x = dpp_add<0xB1>(x);    // xor 1
  x = dpp_add<0x4E>(x);    // xor 2
  x = dpp_add<0x141>(x);   // half_mirror (xor4 effect after quad stages)
  x = dpp_add<0x140>(x);   // row_mirror  (xor8 effect)
  return x;
}

struct Coef { float a[8]; float K; };   // sigma(u) ~ 0.5 + u*q(u^2), |u|<=K

// One register block: 16 timesteps of (eps,hs) = 8 float4 = 32 VGPRs.
struct Blk { float4 q[8]; };
__device__ __forceinline__ void load_blk(const float4* __restrict__ src,
                                         Blk& b) {
#pragma unroll
  for (int i = 0; i < 8; ++i) b.q[i] = src[i];   // broadcast within 16 lanes
}

struct Pre { float dpre[TB - 1]; float hwn[TB]; float eps15; };
__device__ __forceinline__ void extract(const Blk& b, float w0j, float w1j,
                                        Pre& p) {
  float eps[TB];
#pragma unroll
  for (int i = 0; i < 8; ++i) {
    eps[2 * i]       = b.q[i].x;
    p.hwn[2 * i]     = -b.q[i].y * w1j;
    eps[2 * i + 1]   = b.q[i].z;
    p.hwn[2 * i + 1] = -b.q[i].w * w1j;
  }
#pragma unroll
  for (int t = 0; t < TB - 1; ++t) p.dpre[t] = (eps[t + 1] - eps[t]) * w0j;
  p.eps15 = eps[TB - 1];
}

// 16 steps, u-form (u = z1).  CHAIN per step (~80 cy, no trans ops):
//   u'fma -> med3 -> u2 -> Estrin -> q -> v1 -> allreduce16 -> u'fma
// s0/output: save V[t] per step; block-end reduce-scatter (unchanged from
// the passing R14).  NOTE: nothing in this function branches at runtime —
// the whole caller loop body must stay ONE basic block so the scheduler can
// sink this RS / hoist next-phase extract into the butterfly stalls.
__device__ __forceinline__ void compute16(const Pre& p, float nextq0x,
                                          float& u, const Coef cf,
                                          float w0j, float c0j, float c1j,
                                          float h0, float h1, int j,
                                          bool hi8, bool hi4, bool hi2,
                                          bool hi1,
                                          float* __restrict__ outp) {
  float V[TB];
#pragma unroll
  for (int t = 0; t < TB; ++t) {
    float uc  = __builtin_amdgcn_fmed3f(u, -cf.K, cf.K);   // clamp
    float u2  = uc * uc;
    float c1u = c1j * uc;                  // parallel with u2
    float c0u = c0j * uc;
    float b0 = fmaf(cf.a[1], u2, cf.a[0]);
    float b1 = fmaf(cf.a[3], u2, cf.a[2]);
    float b2 = fmaf(cf.a[5], u2, cf.a[4]);
    float b3 = fmaf(cf.a[7], u2, cf.a[6]);
    float u4 = u2 * u2;
    float d0 = fmaf(b1, u4, b0);
    float d1 = fmaf(b3, u4, b2);
    float u8 = u4 * u4;
    float q  = fmaf(d1, u8, d0);           // q(u^2)
    float v1 = fmaf(c1u, q, h1);           // c1 * sigma  (chain)
    V[t]     = fmaf(c0u, q, h0);           // c0 * sigma  (saved, no reduce)
    float s1 = allreduce16(v1);            // gamma-path sum (chain)
    // dpre: last step peeks the next block's first eps UNCONDITIONALLY —
    // for the final block that value only affects u after the last output.
    float dpre_t = (t < TB - 1) ? p.dpre[t]
                                : ((nextq0x - p.eps15) * w0j);
    float P = u + dpre_t;                  // off-chain
    u = fmaf(p.hwn[t], s1, P);             // u' (chain tail)
  }
  // ---- deferred reduce-scatter: lane j <- sum over lanes of V[j] ----
#pragma unroll
  for (int t = 0; t < TB; ++t) V[t] = dpp_add<0x140>(V[t]);  // xor 15
  float W[8];
#pragma unroll
  for (int k = 0; k < 8; ++k) W[k] = hi8 ? V[k + 8] : V[k];
#pragma unroll
  for (int k = 0; k < 8; ++k) W[k] = dpp_add<0x141>(W[k]);   // xor 7
  float X[4];
#pragma unroll
  for (int k = 0; k < 4; ++k) X[k] = hi4 ? W[k + 4] : W[k];
#pragma unroll
  for (int k = 0; k < 4; ++k) X[k] = dpp_add<0x4E>(X[k]);    // xor 2
  float Y0 = hi2 ? X[2] : X[0];
  float Y1 = hi2 ? X[3] : X[1];
  Y0 = dpp_add<0xB1>(Y0);                                    // xor 1
  Y1 = dpp_add<0xB1>(Y1);
  outp[j] = hi1 ? Y1 : Y0;   // 16 consecutive floats per row per block
}

__global__ __launch_bounds__(64) void gsm_scan_kernel(
    const float* __restrict__ inp, const float* __restrict__ W1f,
    const float* __restrict__ b1f, const float* __restrict__ W2f,
    float* __restrict__ out, const Coef cf) {
  const int lane = threadIdx.x;       // 0..63
  const int grp  = lane >> 4;         // row within wave, 0..3
  const int j    = lane & 15;         // hidden unit
  const int row  = (blockIdx.x << 2) + grp;
  const bool hi8 = (j & 8) != 0, hi4 = (j & 4) != 0,
             hi2 = (j & 2) != 0, hi1 = (j & 1) != 0;

  const float w0j = W1f[j];
  const float w1j = W1f[16 + j];
  const float bj  = b1f[j];
  const float w2j = W2f[j];
  const float c0j = w2j * w0j;          // output-path coefficient
  const float c1j = 0.1f * w2j * w1j;   // gamma-path coeff (inv_eta folded)
  const float h0  = 0.5f * c0j;
  const float h1  = 0.5f * c1j;

  const float4* src = (const float4*)(inp + (size_t)row * (2 * T_LEN));
  float* outrow = out + (size_t)row * T_LEN;

  Blk A, Bb;
  Pre p;
  load_blk(src, A);                  // block 0
  load_blk(src + 8, Bb);             // block 1
  float u = fmaf(A.q[0].x, w0j, bj);   // u0 = eps0*w0 + b  (gamma0 = 0)

#pragma unroll 1
  for (int b = 0; b < NBLK; b += 2) {
    // Prefetches are UNCONDITIONAL with wrapped indices: no runtime branch
    // -> the whole loop body is one basic block -> the scheduler can sink
    // the reduce-scatter / hoist extract into the butterfly stalls.
    // Wrapped loads read valid memory whose values are never consumed.
    // ---- phase 1: block b from A; prefetch (b+2)&127 into A's dead regs
    extract(A, w0j, w1j, p);
    load_blk(src + (size_t)((b + 2) & (NBLK - 1)) * 8, A);
    compute16(p, Bb.q[0].x, u, cf, w0j, c0j, c1j, h0, h1, j,
              hi8, hi4, hi2, hi1, outrow + b * TB);
    // ---- phase 2: block b+1 from Bb; prefetch (b+3)&127 into Bb's regs
    extract(Bb, w0j, w1j, p);
    load_blk(src + (size_t)((b + 3) & (NBLK - 1)) * 8, Bb);
    compute16(p, A.q[0].x, u, cf, w0j, c0j, c1j, h0, h1, j,
              hi8, hi4, hi2, hi1, outrow + (b + 1) * TB);
  }
}

// ---- host-side: LS fit of sigma(u)-0.5 with odd poly, deg 15, on [-K,K] ----
static void fit_sigma_coeffs(double K, Coef& cf) {
  const int N = 1024;
  double M[8][8] = {{0}}, bv[8] = {0}, a[8];
  for (int i = 0; i < N; ++i) {
    double th = 3.14159265358979323846 * (i + 0.5) / (2.0 * N);
    double s  = cos(th);                 // Chebyshev-clustered in (0,1]
    double u  = K * s;
    double f  = 1.0 / (1.0 + exp(-u)) - 0.5;
    double pk[8]; double sp = s;
    for (int k = 0; k < 8; ++k) { pk[k] = sp; sp *= s * s; }
    for (int r = 0; r < 8; ++r) {
      bv[r] += f * pk[r];
      for (int c = 0; c < 8; ++c) M[r][c] += pk[r] * pk[c];
    }
  }
  for (int col = 0; col < 8; ++col) {         // Gauss, partial pivoting
    int piv = col;
    for (int r = col + 1; r < 8; ++r)
      if (fabs(M[r][col]) > fabs(M[piv][col])) piv = r;
    if (piv != col) {
      for (int c = 0; c < 8; ++c) { double t = M[col][c]; M[col][c] = M[piv][c]; M[piv][c] = t; }
      double t = bv[col]; bv[col] = bv[piv]; bv[piv] = t;
    }
    for (int r = col + 1; r < 8; ++r) {
      double fac = M[r][col] / M[col][col];
      for (int c = col; c < 8; ++c) M[r][c] -= fac * M[col][c];
      bv[r] -= fac * bv[col];
    }
  }
  for (int r = 7; r >= 0; --r) {
    double s2 = bv[r];
    for (int c = r + 1; c < 8; ++c) s2 -= M[r][c] * a[c];
    a[r] = s2 / M[r][r];
  }
  double Kp = K;                              // rescale s=u/K -> monomials in u
  for (int k = 0; k < 8; ++k) { cf.a[k] = (float)(a[k] / Kp); Kp *= K * K; }
  cf.K = (float)K;
}

extern "C" void kernel_launch(void* const* d_in, const int* in_sizes, int n_in,
                              void* d_out, int out_size, void* d_ws,
                              size_t ws_size, hipStream_t stream) {
  const float* inp = (const float*)d_in[0];   // (B, T, 2) f32
  const float* W1  = (const float*)d_in[1];   // (2, 16)
  const float* b1  = (const float*)d_in[2];   // (16,)
  const float* W2  = (const float*)d_in[3];   // (16, 1)
  // d_in[4] = b2 : unused by the reference computation
  float* out = (float*)d_out;                 // (B, T) f32

  Coef cf;
  fit_sigma_coeffs(6.5, cf);   // deterministic, host-only, runs at capture

  dim3 grid(B_ROWS / 4);   // 1024 waves = 1 per SIMD; wall = steps x chain
  dim3 block(64);
  hipLaunchKernelGGL(gsm_scan_kernel, grid, block, 0, stream,
                     inp, W1, b1, W2, out, cf);
}